// Round 15
// baseline (6880.812 us; speedup 1.0000x reference)
//
#include <hip/hip_runtime.h>

#define H 1024
#define V 32000
#define NSTEP 128
#define LBLK 1000        // logits blocks
#define LROWS 32         // rows per logits block
#define LTHR 512
#define NBLK_L 256       // fused LSTM kernel blocks
#define NTHR_L 512
#define RESCUE_TAU 0.1f

// ws float offsets
#define WS_G0    0        // [2][4096]  gate preact, parity
#define WS_HINIT 8192     // [1024]
#define WS_C0    9216     // [2][1024]  parity
#define WS_H1    11264    // [2][1024]  parity
#define WS_C1    13312    // [1024]
#define WS_PM1   14336    // [LBLK] block max1
#define WS_PIX1  16384    // [LBLK] int
#define WS_PM2   18432    // [LBLK] block max2
#define WS_PIX2  20480    // [LBLK] int
#define WS_WBF   24576    // bf16 Wout: 32768000 ushorts = 16384000 float slots
#define WS_BF_BYTES_NEEDED ((size_t)(WS_WBF + 16384000) * 4)

__device__ __forceinline__ float sigmoidf_(float x) { return 1.f / (1.f + expf(-x)); }

__device__ __forceinline__ float wred(float a) {
#pragma unroll
    for (int o = 32; o > 0; o >>= 1) a += __shfl_down(a, o, 64);
    return a;   // valid in lane 0
}

__device__ __forceinline__ float dot_row(const float4* __restrict__ w4,
                                         const float4* h, int lane) {
    float a = 0.f;
#pragma unroll
    for (int k = 0; k < 4; ++k) {
        float4 w = w4[lane + (k << 6)];
        a += w.x * h[k].x + w.y * h[k].y + w.z * h[k].z + w.w * h[k].w;
    }
    return a;
}

// bf16 helpers
__device__ __forceinline__ unsigned bf16rne(float f) {
    unsigned u = __float_as_uint(f);
    return (u + 0x7FFFu + ((u >> 16) & 1u)) >> 16;
}
__device__ __forceinline__ unsigned pack2(float a, float b) {
    return bf16rne(a) | (bf16rne(b) << 16);
}
__device__ __forceinline__ float bl(unsigned u) { return __uint_as_float(u << 16); }
__device__ __forceinline__ float bh(unsigned u) { return __uint_as_float(u & 0xffff0000u); }

__device__ __forceinline__ float dotbf(const uint4& qa, const uint4& qb,
                                       const float4& ha, const float4& hb,
                                       const float4& hc, const float4& hd) {
    float a = 0.f;
    a += bl(qa.x)*ha.x + bh(qa.x)*ha.y + bl(qa.y)*ha.z + bh(qa.y)*ha.w;
    a += bl(qa.z)*hb.x + bh(qa.z)*hb.y + bl(qa.w)*hb.z + bh(qa.w)*hb.w;
    a += bl(qb.x)*hc.x + bh(qb.x)*hc.y + bl(qb.y)*hc.z + bh(qb.y)*hc.w;
    a += bl(qb.z)*hd.x + bh(qb.z)*hd.y + bl(qb.w)*hd.z + bh(qb.w)*hd.w;
    return a;
}

// ordered top-k updates (jnp.argmax tie-break: lower index wins)
__device__ __forceinline__ void upd2(float v, int r, float& m1, int& i1,
                                     float& m2, int& i2) {
    if (v > m1 || (v == m1 && r < i1)) { m2 = m1; i2 = i1; m1 = v; i1 = r; }
    else if (v > m2 || (v == m2 && r < i2)) { m2 = v; i2 = r; }
}
__device__ __forceinline__ void upd3(float v, int r, float& m1, int& i1,
                                     float& m2, int& i2, float& m3, int& i3) {
    if (v > m1 || (v == m1 && r < i1)) { m3 = m2; i3 = i2; m2 = m1; i2 = i1; m1 = v; i1 = r; }
    else if (v > m2 || (v == m2 && r < i2)) { m3 = m2; i3 = i2; m2 = v; i2 = r; }
    else if (v > m3 || (v == m3 && r < i3)) { m3 = v; i3 = r; }
}

// ---- setup: h_init = Wup @ (cv0*cv1) + bup ; init state ----
__global__ __launch_bounds__(256) void k_setup(const float* __restrict__ Wup,
                                               const float* __restrict__ bup,
                                               const float* __restrict__ cv,
                                               float* __restrict__ ws) {
    int r = blockIdx.x, t = threadIdx.x;   // 1024 blocks
    __shared__ float red[256];
    const float* row = Wup + (size_t)r * H;
    float acc = 0.f;
    for (int j = t; j < H; j += 256) acc += row[j] * (cv[j] * cv[H + j]);
    red[t] = acc;
    __syncthreads();
    for (int s = 128; s > 0; s >>= 1) { if (t < s) red[t] += red[t + s]; __syncthreads(); }
    if (t == 0) {
        float h = red[0] + bup[r];
        ws[WS_HINIT + r] = h;
        ws[WS_C0 + r] = h;       // parity 0
        ws[WS_H1 + r] = h;       // parity 0
        ws[WS_C1 + r] = h;
    }
}

// ---- G0(0) = Whh0 @ h_init + bih0 + bhh0 ----
__global__ __launch_bounds__(256) void k_g0(const float* __restrict__ Whh0,
                                            const float* __restrict__ bih0,
                                            const float* __restrict__ bhh0,
                                            float* __restrict__ ws) {
    int b = blockIdx.x, t = threadIdx.x;
    int w = t >> 6, lane = t & 63;
    float4 hreg[4];
#pragma unroll
    for (int k = 0; k < 4; ++k) hreg[k] = ((const float4*)(ws + WS_HINIT))[lane + (k << 6)];
    int r = (b << 2) + w;
    float a = wred(dot_row((const float4*)(Whh0 + (size_t)r * H), hreg, lane));
    if (lane == 0) ws[WS_G0 + r] = a + bih0[r] + bhh0[r];
}

// ---- convert Wout fp32 -> bf16 (RNE) into ws ----
__global__ __launch_bounds__(256) void k_convert(const float* __restrict__ Wout,
                                                 float* __restrict__ ws) {
    uint4* dst = (uint4*)(ws + WS_WBF);
    const int gid = blockIdx.x * 256 + threadIdx.x;
    const int nth = gridDim.x * 256;
    const int nchunk = (V * H) / 8;   // 4,096,000 chunks of 8 floats
    for (int c = gid; c < nchunk; c += nth) {
        float4 f0 = ((const float4*)Wout)[2 * c];
        float4 f1 = ((const float4*)Wout)[2 * c + 1];
        uint4 o;
        o.x = pack2(f0.x, f0.y); o.y = pack2(f0.z, f0.w);
        o.z = pack2(f1.x, f1.y); o.w = pack2(f1.z, f1.w);
        dst[c] = o;
    }
}

// ---- fused LSTM kernel: top-3 merge + rescue -> tok ; lstm0-finish ;
//      lstm1 matvec ; G0(next) ----
__global__ __launch_bounds__(NTHR_L) void k_L(
    const int* __restrict__ y,
    const float* __restrict__ Wih0col,
    const float* __restrict__ Whh0,
    const float* __restrict__ bih0, const float* __restrict__ bhh0,
    const float* __restrict__ Wih1, const float* __restrict__ Whh1,
    const float* __restrict__ bih1, const float* __restrict__ bhh1,
    const float* __restrict__ WoutF, const float* __restrict__ bout,
    float* __restrict__ ws, int step)
{
    const int b = blockIdx.x, t = threadIdx.x;
    const int w = t >> 6, lane = t & 63;
    const int p = step & 1;
    __shared__ float h0s[H];
    __shared__ float s1v[NTHR_L], s2v[NTHR_L], s3v[NTHR_L];
    __shared__ int   s1i[NTHR_L], s2i[NTHR_L], s3i[NTHR_L];
    __shared__ float gl[4][4];
    __shared__ float rv[3];
    __shared__ int   rj[3];

    // ---- phase 1a: token from prev-step partials (top-3 + fp32 rescue) ----
    float tok;
    if (step == 0) {
        tok = (float)y[0];
    } else {
        float a1 = -1e30f, a2 = -1e30f, a3 = -1e30f;
        int j1 = 0x7fffffff, j2 = 0x7fffffff, j3 = 0x7fffffff;
        for (int i = t; i < LBLK; i += NTHR_L) {
            upd3(ws[WS_PM1 + i], ((const int*)ws)[WS_PIX1 + i], a1, j1, a2, j2, a3, j3);
            upd3(ws[WS_PM2 + i], ((const int*)ws)[WS_PIX2 + i], a1, j1, a2, j2, a3, j3);
        }
        s1v[t] = a1; s1i[t] = j1; s2v[t] = a2; s2i[t] = j2; s3v[t] = a3; s3i[t] = j3;
        __syncthreads();
        for (int o = NTHR_L >> 1; o > 0; o >>= 1) {
            if (t < o) {
                float c1 = s1v[t], c2 = s2v[t], c3 = s3v[t];
                int   d1 = s1i[t], d2 = s2i[t], d3 = s3i[t];
                upd3(s1v[t + o], s1i[t + o], c1, d1, c2, d2, c3, d3);
                upd3(s2v[t + o], s2i[t + o], c1, d1, c2, d2, c3, d3);
                upd3(s3v[t + o], s3i[t + o], c1, d1, c2, d2, c3, d3);
                s1v[t] = c1; s1i[t] = d1; s2v[t] = c2; s2i[t] = d2; s3v[t] = c3; s3i[t] = d3;
            }
            __syncthreads();
        }
        float g1 = s1v[0], g2 = s2v[0];
        int   c1 = s1i[0], c2 = s2i[0], c3 = s3i[0];
        if (g1 - g2 < RESCUE_TAU) {
            // fp32 recompute of the 3 candidates (waves 0..2, one row each)
            if (w < 3) {
                int r = (w == 0) ? c1 : ((w == 1) ? c2 : c3);
                float val = -1e30f;
                if (r != 0x7fffffff) {
                    const float4* wr = (const float4*)(WoutF + (size_t)r * H);
                    const float4* h4 = (const float4*)(ws + WS_H1 + p * H);
                    float d = 0.f;
#pragma unroll
                    for (int k = 0; k < 4; ++k) {
                        float4 wv = wr[lane + (k << 6)];
                        float4 hv = h4[lane + (k << 6)];
                        d += wv.x * hv.x + wv.y * hv.y + wv.z * hv.z + wv.w * hv.w;
                    }
                    d = wred(d);
                    val = fmaxf(d + bout[r], 0.f);
                }
                if (lane == 0) { rv[w] = val; rj[w] = r; }
            }
            __syncthreads();
            float bv = rv[0]; int bj = rj[0];
#pragma unroll
            for (int k = 1; k < 3; ++k)
                if (rv[k] > bv || (rv[k] == bv && rj[k] < bj)) { bv = rv[k]; bj = rj[k]; }
            tok = (float)bj;
        } else {
            tok = (float)c1;
        }
        __syncthreads();
    }

    // ---- phase 1b: finish lstm0 redundantly; h0_new -> LDS; c0 parity flip ----
    for (int c = t; c < H; c += NTHR_L) {
        float gi = ws[WS_G0 + p * 4096 + c]        + Wih0col[c]        * tok;
        float gf = ws[WS_G0 + p * 4096 + 1024 + c] + Wih0col[1024 + c] * tok;
        float gg = ws[WS_G0 + p * 4096 + 2048 + c] + Wih0col[2048 + c] * tok;
        float go = ws[WS_G0 + p * 4096 + 3072 + c] + Wih0col[3072 + c] * tok;
        float cc = sigmoidf_(gf) * ws[WS_C0 + p * H + c] + sigmoidf_(gi) * tanhf(gg);
        ws[WS_C0 + (p ^ 1) * H + c] = cc;
        h0s[c] = sigmoidf_(go) * tanhf(cc);
    }
    __syncthreads();

    // ---- phase 2: lstm1 matvec + G0(next) ----
    float4 hx[4], hh[4];
#pragma unroll
    for (int k = 0; k < 4; ++k) {
        hx[k] = ((const float4*)h0s)[lane + (k << 6)];
        hh[k] = ((const float4*)(ws + WS_H1 + p * H))[lane + (k << 6)];
    }
    {
        const int cell = (b << 2) + (w >> 1);
        const int r0 = cell + ((w & 1) << 11);
        const int r1 = r0 + 1024;
        float a0 = dot_row((const float4*)(Wih1 + (size_t)r0 * H), hx, lane)
                 + dot_row((const float4*)(Whh1 + (size_t)r0 * H), hh, lane);
        float a1 = dot_row((const float4*)(Wih1 + (size_t)r1 * H), hx, lane)
                 + dot_row((const float4*)(Whh1 + (size_t)r1 * H), hh, lane);
        a0 = wred(a0); a1 = wred(a1);
        if (lane == 0) {
            int gi = (w & 1) << 1;
            gl[w >> 1][gi]     = a0 + bih1[r0] + bhh1[r0];
            gl[w >> 1][gi + 1] = a1 + bih1[r1] + bhh1[r1];
        }
    }
    {
        const int g0r = (b << 4) + (w << 1);
        float b0 = dot_row((const float4*)(Whh0 + (size_t)g0r * H), hx, lane);
        float b1 = dot_row((const float4*)(Whh0 + (size_t)(g0r + 1) * H), hx, lane);
        b0 = wred(b0); b1 = wred(b1);
        if (lane == 0) {
            ws[WS_G0 + (p ^ 1) * 4096 + g0r]     = b0 + bih0[g0r] + bhh0[g0r];
            ws[WS_G0 + (p ^ 1) * 4096 + g0r + 1] = b1 + bih0[g0r + 1] + bhh0[g0r + 1];
        }
    }
    __syncthreads();
    if (t < 4) {
        int cell = (b << 2) + t;
        float ig = sigmoidf_(gl[t][0]);
        float fg = sigmoidf_(gl[t][1]);
        float gg = tanhf(gl[t][2]);
        float og = sigmoidf_(gl[t][3]);
        float cc = fg * ws[WS_C1 + cell] + ig * gg;
        ws[WS_C1 + cell] = cc;
        ws[WS_H1 + (p ^ 1) * H + cell] = og * tanhf(cc);
    }
}

// ---- logits bf16: relu(Wbf@h1+bout) -> out row ; block top-2 partials ----
__global__ __launch_bounds__(LTHR) void k_logits_bf(const float* __restrict__ bout,
                                                    float* __restrict__ outrow,
                                                    float* __restrict__ ws, int par) {
    __shared__ float wm1[8], wm2[8];
    __shared__ int   wi1[8], wi2[8];
    int b = blockIdx.x, t = threadIdx.x;
    int w = t >> 6, lane = t & 63;      // 8 waves
    const float4* h4 = (const float4*)(ws + WS_H1 + par * H);
    float4 ha = h4[2 * lane], hb = h4[2 * lane + 1];
    float4 hc = h4[2 * lane + 128], hd = h4[2 * lane + 129];
    const uint4* wb = (const uint4*)(ws + WS_WBF);
    float m1 = -1e30f, m2 = -1e30f;
    int i1 = 0x7fffffff, i2 = 0x7fffffff;
    const int rbase = b * LROWS + (w << 2);   // 4 rows per wave
#pragma unroll
    for (int rr = 0; rr < 4; rr += 2) {
        int r = rbase + rr;
        const uint4* r0p = wb + (size_t)r * 128;
        const uint4* r1p = wb + (size_t)(r + 1) * 128;
        uint4 qa0 = r0p[lane], qb0 = r0p[lane + 64];
        uint4 qa1 = r1p[lane], qb1 = r1p[lane + 64];
        float a0 = wred(dotbf(qa0, qb0, ha, hb, hc, hd));
        float a1 = wred(dotbf(qa1, qb1, ha, hb, hc, hd));
        if (lane == 0) {
            float v0 = fmaxf(a0 + bout[r], 0.f);
            float v1 = fmaxf(a1 + bout[r + 1], 0.f);
            outrow[r] = v0; outrow[r + 1] = v1;
            upd2(v0, r, m1, i1, m2, i2);
            upd2(v1, r + 1, m1, i1, m2, i2);
        }
    }
    if (lane == 0) { wm1[w] = m1; wi1[w] = i1; wm2[w] = m2; wi2[w] = i2; }
    __syncthreads();
    if (t == 0) {
        float g1 = -1e30f, g2 = -1e30f;
        int j1 = 0x7fffffff, j2 = 0x7fffffff;
#pragma unroll
        for (int k = 0; k < 8; ++k) {
            upd2(wm1[k], wi1[k], g1, j1, g2, j2);
            upd2(wm2[k], wi2[k], g1, j1, g2, j2);
        }
        ws[WS_PM1 + b] = g1; ((int*)ws)[WS_PIX1 + b] = j1;
        ws[WS_PM2 + b] = g2; ((int*)ws)[WS_PIX2 + b] = j2;
    }
}

// ---- logits fp32 fallback (same partial format) ----
__global__ __launch_bounds__(LTHR) void k_logits_f32(const float* __restrict__ Wout,
                                                     const float* __restrict__ bout,
                                                     float* __restrict__ outrow,
                                                     float* __restrict__ ws, int par) {
    __shared__ float wm1[8], wm2[8];
    __shared__ int   wi1[8], wi2[8];
    int b = blockIdx.x, t = threadIdx.x;
    int w = t >> 6, lane = t & 63;
    float4 hreg[4];
#pragma unroll
    for (int k = 0; k < 4; ++k)
        hreg[k] = ((const float4*)(ws + WS_H1 + par * H))[lane + (k << 6)];
    float m1 = -1e30f, m2 = -1e30f;
    int i1 = 0x7fffffff, i2 = 0x7fffffff;
    const int rbase = b * LROWS + (w << 2);
#pragma unroll
    for (int rr = 0; rr < 4; rr += 2) {
        int r = rbase + rr;
        float a0 = wred(dot_row((const float4*)(Wout + (size_t)r * H), hreg, lane));
        float a1 = wred(dot_row((const float4*)(Wout + (size_t)(r + 1) * H), hreg, lane));
        if (lane == 0) {
            float v0 = fmaxf(a0 + bout[r], 0.f);
            float v1 = fmaxf(a1 + bout[r + 1], 0.f);
            outrow[r] = v0; outrow[r + 1] = v1;
            upd2(v0, r, m1, i1, m2, i2);
            upd2(v1, r + 1, m1, i1, m2, i2);
        }
    }
    if (lane == 0) { wm1[w] = m1; wi1[w] = i1; wm2[w] = m2; wi2[w] = i2; }
    __syncthreads();
    if (t == 0) {
        float g1 = -1e30f, g2 = -1e30f;
        int j1 = 0x7fffffff, j2 = 0x7fffffff;
#pragma unroll
        for (int k = 0; k < 8; ++k) {
            upd2(wm1[k], wi1[k], g1, j1, g2, j2);
            upd2(wm2[k], wi2[k], g1, j1, g2, j2);
        }
        ws[WS_PM1 + b] = g1; ((int*)ws)[WS_PIX1 + b] = j1;
        ws[WS_PM2 + b] = g2; ((int*)ws)[WS_PIX2 + b] = j2;
    }
}

// ---- final: per-row logsumexp from stored logits, subtract ----
__global__ __launch_bounds__(1024) void k_final(float* __restrict__ out) {
    __shared__ float rm[1024], rs[1024];
    int s = blockIdx.x, t = threadIdx.x;
    float* row = out + (size_t)s * V;
    float m = -1e30f, sum = 0.f;
    for (int i = t; i < V; i += 1024) {
        float v = row[i];
        if (v > m) { sum = sum * expf(m - v) + 1.f; m = v; }
        else         sum += expf(v - m);
    }
    rm[t] = m; rs[t] = sum;
    __syncthreads();
    for (int o = 512; o > 0; o >>= 1) {
        if (t < o) {
            float m2 = rm[t + o], s2 = rs[t + o];
            if (m2 > rm[t]) { rs[t] = rs[t] * expf(rm[t] - m2) + s2; rm[t] = m2; }
            else              rs[t] += s2 * expf(m2 - rm[t]);
        }
        __syncthreads();
    }
    float logz = rm[0] + logf(rs[0]);
    for (int i = t; i < V; i += 1024) row[i] -= logz;
}

extern "C" void kernel_launch(void* const* d_in, const int* in_sizes, int n_in,
                              void* d_out, int out_size, void* d_ws, size_t ws_size,
                              hipStream_t stream) {
    const int*   y    = (const int*)d_in[0];
    const float* cv   = (const float*)d_in[1];
    const float* Wup  = (const float*)d_in[3];
    const float* bup  = (const float*)d_in[4];
    const float* Wih0 = (const float*)d_in[5];   // [4096,1] column
    const float* Whh0 = (const float*)d_in[6];
    const float* bih0 = (const float*)d_in[7];
    const float* bhh0 = (const float*)d_in[8];
    const float* Wih1 = (const float*)d_in[9];
    const float* Whh1 = (const float*)d_in[10];
    const float* bih1 = (const float*)d_in[11];
    const float* bhh1 = (const float*)d_in[12];
    const float* Wout = (const float*)d_in[13];
    const float* bout = (const float*)d_in[14];
    float* out = (float*)d_out;
    float* ws  = (float*)d_ws;

    const bool bf = (ws_size >= WS_BF_BYTES_NEEDED);   // constant across calls

    k_setup<<<1024, 256, 0, stream>>>(Wup, bup, cv, ws);
    k_g0<<<1024, 256, 0, stream>>>(Whh0, bih0, bhh0, ws);
    if (bf) k_convert<<<2048, 256, 0, stream>>>(Wout, ws);
    for (int t = 0; t < NSTEP; ++t) {
        k_L<<<NBLK_L, NTHR_L, 0, stream>>>(y, Wih0, Whh0, bih0, bhh0,
                                           Wih1, Whh1, bih1, bhh1,
                                           Wout, bout, ws, t);
        if (bf)
            k_logits_bf<<<LBLK, LTHR, 0, stream>>>(bout, out + (size_t)t * V, ws, (t & 1) ^ 1);
        else
            k_logits_f32<<<LBLK, LTHR, 0, stream>>>(Wout, bout, out + (size_t)t * V, ws, (t & 1) ^ 1);
    }
    k_final<<<NSTEP, 1024, 0, stream>>>(out);
}